// Round 6
// baseline (330.237 us; speedup 1.0000x reference)
//
#include <hip/hip_runtime.h>

#define HID 50
#define IND 8
#define TLEN 512
#define NB 32        // TWO 16-col groups per block (A: n 0-15, B: n 16-31)
#define CH 128       // x chunk timesteps staged in LDS (4 chunks/sequence)
#define XTS 264      // x_frag per-timestep stride in halves (528B = 132 dw = 4 mod 32)
#define NTHR 448     // 7 waves, 2 M-tiles each per group (tiles 0..13)

typedef _Float16 f16x8 __attribute__((ext_vector_type(8)));
typedef _Float16 f16x4 __attribute__((ext_vector_type(4)));
typedef _Float16 f16x2 __attribute__((ext_vector_type(2)));
typedef float f32x4 __attribute__((ext_vector_type(4)));

// Round-16: dual-group interval amortization.
//  Evidence R1-R5: the 806-cyc step interval is a latency/sync floor
//  (issue floor ~300 cyc); throughput cuts vanish into bubbles; wall
//  = 512 x interval. So: double the independent work per interval.
//  NB=32: two 16-col groups interleaved in one step body, one barrier.
//  Group B's reads/MFMAs/gates fill group A's latency bubbles inside
//  each wave; 7 waves keep ~2 waves/SIMD TLP (R4 lesson). A-fragments
//  and biases shared across groups (same weights). Grid 128 blocks --
//  half the CUs idle, wall-clock set by interval, not utilization.
//  R5 lessons: no stager wave (__syncthreads drains vmcnt per wave);
//  chained bias-seeded MFMA (unchaining paid 4 adds for nothing).
__global__ __launch_bounds__(NTHR, 1) void gru_mfma12(
    const float* __restrict__ x,      // [B, T, 8]
    const float* __restrict__ W_ih,   // [150, 8]
    const float* __restrict__ W_hh,   // [150, 50]
    const float* __restrict__ b_ih,   // [150]
    const float* __restrict__ b_hh,   // [150]
    const float* __restrict__ W_out,  // [1, 50]
    const float* __restrict__ b_out,  // [1]
    float* __restrict__ out)          // [B]
{
    const int tid  = threadIdx.x;     // 448 threads = 7 waves
    const int wave = tid >> 6;
    const int lane = tid & 63;
    const int m16  = lane & 15;
    const int quad = lane >> 4;
    const int bb   = blockIdx.x;

    const int t0  = 2 * wave;         // tiles; R = 16*t + m16; R = 4*jh + g
    const int t1  = 2 * wave + 1;
    const int jh0 = 8 * wave + quad;
    const int jh1 = 8 * wave + 4 + quad;

    // B panels: [grp 0/1][buf 0/1][7 kgrps][16 slots][8 halves]
    __shared__ _Float16 B_lds[2 * 2 * 896];
    __shared__ _Float16 x_frag[CH * XTS];     // 67.6 KB fragment-ordered x (32 cols)
    __shared__ float    red[NB * 56];         // head scratch, 7 KB

    const int P[8] = {0, 4, 1, 5, 2, 6, 3, 7};

    // ---- one-time: A fragments + biases into VGPRs, scales prefolded ----
    auto aval = [&](int tt, int k) -> float {
        const int R  = 16 * tt + m16;
        const int rj = R >> 2;
        const int g  = R & 3;
        if (rj >= HID) return 0.f;
        const float sc = (g <= 1) ? -1.44269504f : 2.88539008f;
        float w = 0.f;
        if (g <= 1) {
            if (k < HID)      w = W_hh[(g * HID + rj) * HID + k];
            else if (k >= 56) w = W_ih[(g * HID + rj) * IND + (k - 56)];
        } else if (g == 2) {
            if (k < HID)      w = W_hh[(2 * HID + rj) * HID + k];
        } else {
            if (k >= 56)      w = W_ih[(2 * HID + rj) * IND + (k - 56)];
        }
        return sc * w;
    };

    f16x8 a00, a01, a10, a11;
#pragma unroll
    for (int p = 0; p < 8; ++p) {
        a00[p] = (_Float16)aval(t0, quad * 8 + P[p]);
        a01[p] = (_Float16)aval(t0, 32 + quad * 8 + P[p]);
        a10[p] = (_Float16)aval(t1, quad * 8 + P[p]);
        a11[p] = (_Float16)aval(t1, 32 + quad * 8 + P[p]);
    }

    auto mkbias = [&](int jh) -> f32x4 {
        f32x4 b = {0.f, 0.f, 0.f, 0.f};
        if (jh < HID) {
            b[0] = -1.44269504f * (b_ih[jh] + b_hh[jh]);
            b[1] = -1.44269504f * (b_ih[HID + jh] + b_hh[HID + jh]);
            b[2] =  2.88539008f * b_hh[2 * HID + jh];
            b[3] =  2.88539008f * b_ih[2 * HID + jh];
        }
        return b;
    };
    const f32x4 bias0 = mkbias(jh0);
    const f32x4 bias1 = mkbias(jh1);

    float h0A = 0.f, h1A = 0.f, h0B = 0.f, h1B = 0.f;

    // ---- x chunk staging: fragment order (32 cols), permuted intra-slot ----
    auto stage_chunk = [&](int c) {
        for (int u = tid; u < NB * CH; u += NTHR) {      // 4096 units
            const int n    = u >> 7;                      // 0..31
            const int trel = u & (CH - 1);
            const float4* s = (const float4*)(x + ((size_t)(bb * NB + n) * TLEN + (size_t)c * CH + trel) * IND);
            const float4 va = s[0];                       // d 0..3
            const float4 vb = s[1];                       // d 4..7
            const f16x4 lo = {(_Float16)va.x, (_Float16)vb.x, (_Float16)va.y, (_Float16)vb.y};
            const f16x4 hi = {(_Float16)va.z, (_Float16)vb.z, (_Float16)va.w, (_Float16)vb.w};
            *(f16x4*)&x_frag[trel * XTS + n * 8]     = lo;
            *(f16x4*)&x_frag[trel * XTS + n * 8 + 4] = hi;
        }
    };

    // ---- init: zero all B panels; stage chunk 0 ----
    for (int idx = tid; idx < 2 * 2 * 896; idx += NTHR)
        B_lds[idx] = (_Float16)0.f;
    stage_chunk(0);
    __syncthreads();

    const int lane8 = lane * 8;                       // halves: lane*16B
    const _Float16* xqA = &x_frag[m16 * 8];           // quad3 x base, group A
    const _Float16* xqB = &x_frag[(16 + m16) * 8];    // quad3 x base, group B
    const int wad = wave * 128 + m16 * 8 + 2 * quad;  // h-write within a panel

    // 5-trans gates (scales prefolded): r = rcp(1+2^c0); Z = 2^c1;
    // E = 2^(c3 + r*c2); h' = (E*(Z+h) + (h-Z)) * rcp((E+1)*(Z+1))
    auto gates = [&](const f32x4& cc, float hh) -> float {
        const float R2 = __builtin_amdgcn_exp2f(cc[0]);
        const float r  = __builtin_amdgcn_rcpf(1.0f + R2);
        const float Z2 = __builtin_amdgcn_exp2f(cc[1]);
        const float E  = __builtin_amdgcn_exp2f(cc[3] + r * cc[2]);
        const float num = E * (Z2 + hh) + (hh - Z2);
        const float den = (E + 1.0f) * (Z2 + 1.0f);
        return num * __builtin_amdgcn_rcpf(den);
    };

    auto step = [&](int i, int cur, int nxt) {
        _Float16* BcA = &B_lds[cur * 896];
        _Float16* BnA = &B_lds[nxt * 896];
        _Float16* BcB = &B_lds[1792 + cur * 896];
        _Float16* BnB = &B_lds[1792 + nxt * 896];
        // all 4 fragment reads issued up front (independent chains)
        const f16x8 bf0A = *(const f16x8*)(BcA + lane8);
        const _Float16* p1A = (quad == 3) ? (xqA + (size_t)i * XTS) : (BcA + 512 + lane8);
        const f16x8 bf1A = *(const f16x8*)p1A;
        const f16x8 bf0B = *(const f16x8*)(BcB + lane8);
        const _Float16* p1B = (quad == 3) ? (xqB + (size_t)i * XTS) : (BcB + 512 + lane8);
        const f16x8 bf1B = *(const f16x8*)p1B;
        // group A MFMAs (chained, bias-seeded)
        f32x4 c0A = __builtin_amdgcn_mfma_f32_16x16x32_f16(a00, bf0A, bias0, 0, 0, 0);
        f32x4 c1A = __builtin_amdgcn_mfma_f32_16x16x32_f16(a10, bf0A, bias1, 0, 0, 0);
        // group B MFMAs interleaved
        f32x4 c0B = __builtin_amdgcn_mfma_f32_16x16x32_f16(a00, bf0B, bias0, 0, 0, 0);
        f32x4 c1B = __builtin_amdgcn_mfma_f32_16x16x32_f16(a10, bf0B, bias1, 0, 0, 0);
        c0A = __builtin_amdgcn_mfma_f32_16x16x32_f16(a01, bf1A, c0A, 0, 0, 0);
        c1A = __builtin_amdgcn_mfma_f32_16x16x32_f16(a11, bf1A, c1A, 0, 0, 0);
        c0B = __builtin_amdgcn_mfma_f32_16x16x32_f16(a01, bf1B, c0B, 0, 0, 0);
        c1B = __builtin_amdgcn_mfma_f32_16x16x32_f16(a11, bf1B, c1B, 0, 0, 0);
        // four independent gate chains interleave in the scheduler
        h0A = gates(c0A, h0A);
        h1A = gates(c1A, h1A);
        h0B = gates(c0B, h0B);
        h1B = gates(c1B, h1B);
        *(f16x2*)(BnA + wad) = f16x2{(_Float16)h0A, (_Float16)h1A};
        *(f16x2*)(BnB + wad) = f16x2{(_Float16)h0B, (_Float16)h1B};
        __syncthreads();   // the only per-step barrier
    };

    // ---- recurrence: 7 waves, both groups, 1 barrier/step ----
    for (int c = 0; c < 4; ++c) {
        if (c != 0) { stage_chunk(c); __syncthreads(); }
#pragma unroll 4
        for (int i = 0; i < CH; i += 2) {
            step(i,     0, 1);
            step(i + 1, 1, 0);
        }
    }

    // ---- head: out[n] = sum_jh h(jh,n) * W_out[jh] + b_out ----
    if (jh0 < HID) {
        red[m16 * 56 + jh0]        = h0A * W_out[jh0];
        red[(16 + m16) * 56 + jh0] = h0B * W_out[jh0];
    }
    if (jh1 < HID) {
        red[m16 * 56 + jh1]        = h1A * W_out[jh1];
        red[(16 + m16) * 56 + jh1] = h1B * W_out[jh1];
    }
    __syncthreads();
    if (tid < NB) {
        float s = b_out[0];
        for (int j = 0; j < HID; ++j) s += red[tid * 56 + j];
        out[bb * NB + tid] = s;
    }
}

extern "C" void kernel_launch(void* const* d_in, const int* in_sizes, int n_in,
                              void* d_out, int out_size, void* d_ws, size_t ws_size,
                              hipStream_t stream) {
    const float* x     = (const float*)d_in[0];
    const float* W_ih  = (const float*)d_in[1];
    const float* W_hh  = (const float*)d_in[2];
    const float* b_ih  = (const float*)d_in[3];
    const float* b_hh  = (const float*)d_in[4];
    const float* W_out = (const float*)d_in[5];
    const float* b_out = (const float*)d_in[6];
    float* out = (float*)d_out;

    const int B = in_sizes[0] / (TLEN * IND);   // 4096
    gru_mfma12<<<B / NB, NTHR, 0, stream>>>(x, W_ih, W_hh, b_ih, b_hh, W_out, b_out, out);
}

// Round 7
// 300.617 us; speedup vs baseline: 1.0985x; 1.0985x over previous
//
#include <hip/hip_runtime.h>

#define HID 50
#define IND 8
#define TLEN 512
#define NB 8         // 8 real batch cols per block -> 512 blocks = 2 blocks/CU
#define CH 128       // x chunk timesteps staged in LDS (4 chunks/sequence)
#define XTS 72       // x_frag per-timestep stride in halves (144B = 36 dw = 4 mod 32)
#define NTHR 448     // 7 waves, 2 M-tiles each (tiles 0..13)

typedef _Float16 f16x8 __attribute__((ext_vector_type(8)));
typedef _Float16 f16x4 __attribute__((ext_vector_type(4)));
typedef _Float16 f16x2 __attribute__((ext_vector_type(2)));
typedef float f32x4 __attribute__((ext_vector_type(4)));

// Round-17: two independent blocks per CU.
//  R6 decomposition: interval = 320 cyc fixed (barrier/latency) + 485 cyc
//  work per 16-col group. The fixed part can only be hidden by a stream
//  with an INDEPENDENT barrier clock -> a second workgroup on the CU.
//  NB=8: 512 blocks, each ~24KB LDS / 448 thr -> 2 co-resident per CU.
//  Per-block instruction stream identical to the NB=16 champion (cols
//  8-15 are dead lanes: MFMA columns are independent, dead h never read
//  back; dead quad3 lanes read a real x copy via m16&7 -> all finite).
//  Per-CU: VALU/trans issue 2x over a ~650-cyc interval, fixed 320 hidden.
__global__ __launch_bounds__(NTHR, 1) void gru_mfma13(
    const float* __restrict__ x,      // [B, T, 8]
    const float* __restrict__ W_ih,   // [150, 8]
    const float* __restrict__ W_hh,   // [150, 50]
    const float* __restrict__ b_ih,   // [150]
    const float* __restrict__ b_hh,   // [150]
    const float* __restrict__ W_out,  // [1, 50]
    const float* __restrict__ b_out,  // [1]
    float* __restrict__ out)          // [B]
{
    const int tid  = threadIdx.x;     // 448 threads = 7 waves
    const int wave = tid >> 6;
    const int lane = tid & 63;
    const int m16  = lane & 15;
    const int quad = lane >> 4;
    const int bb   = blockIdx.x;

    const int t0  = 2 * wave;         // tiles; R = 16*t + m16; R = 4*jh + g
    const int t1  = 2 * wave + 1;
    const int jh0 = 8 * wave + quad;
    const int jh1 = 8 * wave + 4 + quad;

    // B buffers: 2 x [7 kgrps][16 slots][8 halves] = 2 x 896 halves
    __shared__ _Float16 B_lds[2 * 896];
    __shared__ _Float16 x_frag[CH * XTS];     // 18.4 KB (8 real cols)
    __shared__ float    red[NB * 56];         // head scratch

    const int P[8] = {0, 4, 1, 5, 2, 6, 3, 7};

    // ---- one-time: A fragments + biases into VGPRs, scales prefolded ----
    auto aval = [&](int tt, int k) -> float {
        const int R  = 16 * tt + m16;
        const int rj = R >> 2;
        const int g  = R & 3;
        if (rj >= HID) return 0.f;
        const float sc = (g <= 1) ? -1.44269504f : 2.88539008f;
        float w = 0.f;
        if (g <= 1) {
            if (k < HID)      w = W_hh[(g * HID + rj) * HID + k];
            else if (k >= 56) w = W_ih[(g * HID + rj) * IND + (k - 56)];
        } else if (g == 2) {
            if (k < HID)      w = W_hh[(2 * HID + rj) * HID + k];
        } else {
            if (k >= 56)      w = W_ih[(2 * HID + rj) * IND + (k - 56)];
        }
        return sc * w;
    };

    f16x8 a00, a01, a10, a11;
#pragma unroll
    for (int p = 0; p < 8; ++p) {
        a00[p] = (_Float16)aval(t0, quad * 8 + P[p]);
        a01[p] = (_Float16)aval(t0, 32 + quad * 8 + P[p]);
        a10[p] = (_Float16)aval(t1, quad * 8 + P[p]);
        a11[p] = (_Float16)aval(t1, 32 + quad * 8 + P[p]);
    }

    auto mkbias = [&](int jh) -> f32x4 {
        f32x4 b = {0.f, 0.f, 0.f, 0.f};
        if (jh < HID) {
            b[0] = -1.44269504f * (b_ih[jh] + b_hh[jh]);
            b[1] = -1.44269504f * (b_ih[HID + jh] + b_hh[HID + jh]);
            b[2] =  2.88539008f * b_hh[2 * HID + jh];
            b[3] =  2.88539008f * b_ih[2 * HID + jh];
        }
        return b;
    };
    const f32x4 bias0 = mkbias(jh0);
    const f32x4 bias1 = mkbias(jh1);

    float h0 = 0.f, h1 = 0.f;

    // ---- x chunk staging: fragment order (8 real cols), permuted ----
    auto stage_chunk = [&](int c) {
        for (int u = tid; u < NB * CH; u += NTHR) {      // 1024 units
            const int n    = u >> 7;                      // 0..7
            const int trel = u & (CH - 1);
            const float4* s = (const float4*)(x + ((size_t)(bb * NB + n) * TLEN + (size_t)c * CH + trel) * IND);
            const float4 va = s[0];                       // d 0..3
            const float4 vb = s[1];                       // d 4..7
            const f16x4 lo = {(_Float16)va.x, (_Float16)vb.x, (_Float16)va.y, (_Float16)vb.y};
            const f16x4 hi = {(_Float16)va.z, (_Float16)vb.z, (_Float16)va.w, (_Float16)vb.w};
            *(f16x4*)&x_frag[trel * XTS + n * 8]     = lo;
            *(f16x4*)&x_frag[trel * XTS + n * 8 + 4] = hi;
        }
    };

    // ---- init: zero both B buffers; stage chunk 0 ----
    for (int idx = tid; idx < 2 * 896; idx += NTHR)
        B_lds[idx] = (_Float16)0.f;
    stage_chunk(0);
    __syncthreads();

    const int lane8 = lane * 8;                        // halves: lane*16B
    // quad3 x base: dead cols (m16>=8) read a REAL x copy -> finite h
    const _Float16* xq = &x_frag[(m16 & 7) * 8];
    const int wad = wave * 128 + m16 * 8 + 2 * quad;   // h-write base

    // 5-trans gates (scales prefolded): r = rcp(1+2^c0); Z = 2^c1;
    // E = 2^(c3 + r*c2); h' = (E*(Z+h) + (h-Z)) * rcp((E+1)*(Z+1))
    auto gates = [&](const f32x4& cc, float hh) -> float {
        const float R2 = __builtin_amdgcn_exp2f(cc[0]);
        const float r  = __builtin_amdgcn_rcpf(1.0f + R2);
        const float Z2 = __builtin_amdgcn_exp2f(cc[1]);
        const float E  = __builtin_amdgcn_exp2f(cc[3] + r * cc[2]);
        const float num = E * (Z2 + hh) + (hh - Z2);
        const float den = (E + 1.0f) * (Z2 + 1.0f);
        return num * __builtin_amdgcn_rcpf(den);
    };

    auto step = [&](int i, int cur, int nxt) {
        _Float16* Bc = &B_lds[cur * 896];
        _Float16* Bn = &B_lds[nxt * 896];
        const f16x8 bf0 = *(const f16x8*)(Bc + lane8);
        const _Float16* p1 = (quad == 3) ? (xq + (size_t)i * XTS) : (Bc + 512 + lane8);
        const f16x8 bf1 = *(const f16x8*)p1;
        f32x4 c0 = __builtin_amdgcn_mfma_f32_16x16x32_f16(a00, bf0, bias0, 0, 0, 0);
        f32x4 c1 = __builtin_amdgcn_mfma_f32_16x16x32_f16(a10, bf0, bias1, 0, 0, 0);
        c0 = __builtin_amdgcn_mfma_f32_16x16x32_f16(a01, bf1, c0, 0, 0, 0);
        c1 = __builtin_amdgcn_mfma_f32_16x16x32_f16(a11, bf1, c1, 0, 0, 0);
        h0 = gates(c0, h0);
        h1 = gates(c1, h1);
        *(f16x2*)(Bn + wad) = f16x2{(_Float16)h0, (_Float16)h1};
        __syncthreads();   // the only per-step barrier
    };

    // ---- recurrence: 7 waves, 1 barrier/step ----
    for (int c = 0; c < 4; ++c) {
        if (c != 0) { stage_chunk(c); __syncthreads(); }
#pragma unroll 4
        for (int i = 0; i < CH; i += 2) {
            step(i,     0, 1);
            step(i + 1, 1, 0);
        }
    }

    // ---- head: out[n] = sum_jh h(jh,n) * W_out[jh] + b_out ----
    if (m16 < NB) {
        if (jh0 < HID) red[m16 * 56 + jh0] = h0 * W_out[jh0];
        if (jh1 < HID) red[m16 * 56 + jh1] = h1 * W_out[jh1];
    }
    __syncthreads();
    if (tid < NB) {
        float s = b_out[0];
        for (int j = 0; j < HID; ++j) s += red[tid * 56 + j];
        out[bb * NB + tid] = s;
    }
}

extern "C" void kernel_launch(void* const* d_in, const int* in_sizes, int n_in,
                              void* d_out, int out_size, void* d_ws, size_t ws_size,
                              hipStream_t stream) {
    const float* x     = (const float*)d_in[0];
    const float* W_ih  = (const float*)d_in[1];
    const float* W_hh  = (const float*)d_in[2];
    const float* b_ih  = (const float*)d_in[3];
    const float* b_hh  = (const float*)d_in[4];
    const float* W_out = (const float*)d_in[5];
    const float* b_out = (const float*)d_in[6];
    float* out = (float*)d_out;

    const int B = in_sizes[0] / (TLEN * IND);   // 4096
    gru_mfma13<<<B / NB, NTHR, 0, stream>>>(x, W_ih, W_hh, b_ih, b_hh, W_out, b_out, out);
}

// Round 8
// 265.509 us; speedup vs baseline: 1.2438x; 1.1322x over previous
//
#include <hip/hip_runtime.h>

#define HID 50
#define IND 8
#define TLEN 512
#define NB 16        // batch columns per block — all 16 MFMA N cols real
#define CH 128       // x chunk timesteps staged in LDS (4 chunks/sequence)
#define XTS 136      // x_frag per-timestep stride in halves (272B: 17*16B)
#define NTHR 448     // 7 waves, 2 M-tiles each (tiles 0..13)

typedef _Float16 f16x8 __attribute__((ext_vector_type(8)));
typedef _Float16 f16x4 __attribute__((ext_vector_type(4)));
typedef _Float16 f16x2 __attribute__((ext_vector_type(2)));
typedef float f32x4 __attribute__((ext_vector_type(4)));

// Round-18: R3 champion with the per-step s_barrier replaced by producer
// flags + SPLIT waits (the sync-floor falsification probe).
//  - wave w publishes wflag[w]=t+1 after lgkmcnt(0)-drained h-write
//  - consumers: wait flags[0..3]>=t -> read bf0 (k 0..31 is waves 0..3's
//    rows); wait flags[4..6]>=t -> read bf1. Early release vs global-slowest
//    barrier; read burst de-bursted.
//  - safety: a wave needs ALL flags >= t to pass step t, and flag t+1 is
//    published only after its step-t reads were consumed (MFMA waits
//    lgkmcnt before gates -> write -> drain -> flag). So no wave can run
//    >1 step ahead of any other: double buffer suffices. Chunk restage
//    keeps hard __syncthreads (3x per kernel).
__global__ __launch_bounds__(NTHR, 1) void gru_mfma14(
    const float* __restrict__ x,      // [B, T, 8]
    const float* __restrict__ W_ih,   // [150, 8]
    const float* __restrict__ W_hh,   // [150, 50]
    const float* __restrict__ b_ih,   // [150]
    const float* __restrict__ b_hh,   // [150]
    const float* __restrict__ W_out,  // [1, 50]
    const float* __restrict__ b_out,  // [1]
    float* __restrict__ out)          // [B]
{
    const int tid  = threadIdx.x;     // 448 threads = 7 waves
    const int wave = tid >> 6;
    const int lane = tid & 63;
    const int m16  = lane & 15;
    const int quad = lane >> 4;
    const int bb   = blockIdx.x;

    const int t0  = 2 * wave;         // tiles; R = 16*t + m16; R = 4*jh + g
    const int t1  = 2 * wave + 1;
    const int jh0 = 8 * wave + quad;
    const int jh1 = 8 * wave + 4 + quad;

    // B buffers: 2 x [7 kgrps][16 slots][8 halves] = 2 x 896 halves
    __shared__ _Float16 B_lds[2 * 896];
    __shared__ _Float16 x_frag[CH * XTS];     // ~34.8 KB fragment-ordered x
    __shared__ float    red[NB * 56];         // head scratch
    __shared__ int      wflag[7 * 8];         // flag[w] at wflag[w*8] (32B apart)

    const int P[8] = {0, 4, 1, 5, 2, 6, 3, 7};

    // ---- one-time: A fragments + biases into VGPRs, scales prefolded ----
    auto aval = [&](int tt, int k) -> float {
        const int R  = 16 * tt + m16;
        const int rj = R >> 2;
        const int g  = R & 3;
        if (rj >= HID) return 0.f;
        const float sc = (g <= 1) ? -1.44269504f : 2.88539008f;
        float w = 0.f;
        if (g <= 1) {
            if (k < HID)      w = W_hh[(g * HID + rj) * HID + k];
            else if (k >= 56) w = W_ih[(g * HID + rj) * IND + (k - 56)];
        } else if (g == 2) {
            if (k < HID)      w = W_hh[(2 * HID + rj) * HID + k];
        } else {
            if (k >= 56)      w = W_ih[(2 * HID + rj) * IND + (k - 56)];
        }
        return sc * w;
    };

    f16x8 a00, a01, a10, a11;
#pragma unroll
    for (int p = 0; p < 8; ++p) {
        a00[p] = (_Float16)aval(t0, quad * 8 + P[p]);
        a01[p] = (_Float16)aval(t0, 32 + quad * 8 + P[p]);
        a10[p] = (_Float16)aval(t1, quad * 8 + P[p]);
        a11[p] = (_Float16)aval(t1, 32 + quad * 8 + P[p]);
    }

    auto mkbias = [&](int jh) -> f32x4 {
        f32x4 b = {0.f, 0.f, 0.f, 0.f};
        if (jh < HID) {
            b[0] = -1.44269504f * (b_ih[jh] + b_hh[jh]);
            b[1] = -1.44269504f * (b_ih[HID + jh] + b_hh[HID + jh]);
            b[2] =  2.88539008f * b_hh[2 * HID + jh];
            b[3] =  2.88539008f * b_ih[2 * HID + jh];
        }
        return b;
    };
    const f32x4 bias0 = mkbias(jh0);
    const f32x4 bias1 = mkbias(jh1);

    float h0 = 0.f, h1 = 0.f;

    // ---- x chunk staging: fragment order, permuted intra-slot ----
    auto stage_chunk = [&](int c) {
        for (int u = tid; u < NB * CH; u += NTHR) {      // 2048 units
            const int n    = u >> 7;
            const int trel = u & (CH - 1);
            const float4* s = (const float4*)(x + ((size_t)(bb * NB + n) * TLEN + (size_t)c * CH + trel) * IND);
            const float4 va = s[0];                       // d 0..3
            const float4 vb = s[1];                       // d 4..7
            const f16x4 lo = {(_Float16)va.x, (_Float16)vb.x, (_Float16)va.y, (_Float16)vb.y};
            const f16x4 hi = {(_Float16)va.z, (_Float16)vb.z, (_Float16)va.w, (_Float16)vb.w};
            *(f16x4*)&x_frag[trel * XTS + n * 8]     = lo;
            *(f16x4*)&x_frag[trel * XTS + n * 8 + 4] = hi;
        }
    };

    // ---- init: zero B buffers + flags; stage chunk 0 ----
    for (int idx = tid; idx < 2 * 896; idx += NTHR)
        B_lds[idx] = (_Float16)0.f;
    if (tid < 56) wflag[tid] = 0;
    stage_chunk(0);
    __syncthreads();

    const int lane8 = lane * 8;                       // halves: lane*16B
    const _Float16* xq = &x_frag[m16 * 8];            // quad3 x base
    const int wad = wave * 128 + m16 * 8 + 2 * quad;  // h-write base

    // per-lane flag poll pointers: lanes cover flags {0..3} and {4,5,6}
    const int l3 = lane & 3;
    volatile int* pfA = (volatile int*)&wflag[l3 * 8];
    volatile int* pfB = (volatile int*)&wflag[(4 + (l3 == 3 ? 0 : l3)) * 8];

    // 5-trans gates (scales prefolded): r = rcp(1+2^c0); Z = 2^c1;
    // E = 2^(c3 + r*c2); h' = (E*(Z+h) + (h-Z)) * rcp((E+1)*(Z+1))
    auto gates = [&](const f32x4& cc, float hh) -> float {
        const float R2 = __builtin_amdgcn_exp2f(cc[0]);
        const float r  = __builtin_amdgcn_rcpf(1.0f + R2);
        const float Z2 = __builtin_amdgcn_exp2f(cc[1]);
        const float E  = __builtin_amdgcn_exp2f(cc[3] + r * cc[2]);
        const float num = E * (Z2 + hh) + (hh - Z2);
        const float den = (E + 1.0f) * (Z2 + 1.0f);
        return num * __builtin_amdgcn_rcpf(den);
    };

    auto step = [&](int i, int cur, int nxt, int tgt) {
        _Float16* Bc = &B_lds[cur * 896];
        _Float16* Bn = &B_lds[nxt * 896];
        // wait for low-K producers (waves 0..3), read bf0 early
        while (__any(*pfA < tgt)) {}
        asm volatile("" ::: "memory");
        const f16x8 bf0 = *(const f16x8*)(Bc + lane8);
        // wait for high-K producers (waves 4..6), read bf1
        while (__any(*pfB < tgt)) {}
        asm volatile("" ::: "memory");
        const _Float16* p1 = (quad == 3) ? (xq + (size_t)i * XTS) : (Bc + 512 + lane8);
        const f16x8 bf1 = *(const f16x8*)p1;
        f32x4 c0 = __builtin_amdgcn_mfma_f32_16x16x32_f16(a00, bf0, bias0, 0, 0, 0);
        f32x4 c1 = __builtin_amdgcn_mfma_f32_16x16x32_f16(a10, bf0, bias1, 0, 0, 0);
        c0 = __builtin_amdgcn_mfma_f32_16x16x32_f16(a01, bf1, c0, 0, 0, 0);
        c1 = __builtin_amdgcn_mfma_f32_16x16x32_f16(a11, bf1, c1, 0, 0, 0);
        h0 = gates(c0, h0);
        h1 = gates(c1, h1);
        *(f16x2*)(Bn + wad) = f16x2{(_Float16)h0, (_Float16)h1};
        // drain the h-write, then publish
        asm volatile("s_waitcnt lgkmcnt(0)" ::: "memory");
        if (lane == 0) *(volatile int*)&wflag[wave * 8] = tgt + 1;
    };

    // ---- recurrence: 7 waves, flag-sync, no per-step barrier ----
    int gt = 0;
    for (int c = 0; c < 4; ++c) {
        if (c != 0) {
            __syncthreads();            // all waves done with old x chunk
            stage_chunk(c);
            __syncthreads();
        }
#pragma unroll 2
        for (int i = 0; i < CH; i += 2) {
            step(i,     0, 1, gt);
            step(i + 1, 1, 0, gt + 1);
            gt += 2;
        }
    }

    // ---- head: out[n] = sum_jh h(jh,n) * W_out[jh] + b_out ----
    if (jh0 < HID) red[m16 * 56 + jh0] = h0 * W_out[jh0];
    if (jh1 < HID) red[m16 * 56 + jh1] = h1 * W_out[jh1];
    __syncthreads();
    if (tid < NB) {
        float s = b_out[0];
        for (int j = 0; j < HID; ++j) s += red[tid * 56 + j];
        out[bb * NB + tid] = s;
    }
}

extern "C" void kernel_launch(void* const* d_in, const int* in_sizes, int n_in,
                              void* d_out, int out_size, void* d_ws, size_t ws_size,
                              hipStream_t stream) {
    const float* x     = (const float*)d_in[0];
    const float* W_ih  = (const float*)d_in[1];
    const float* W_hh  = (const float*)d_in[2];
    const float* b_ih  = (const float*)d_in[3];
    const float* b_hh  = (const float*)d_in[4];
    const float* W_out = (const float*)d_in[5];
    const float* b_out = (const float*)d_in[6];
    float* out = (float*)d_out;

    const int B = in_sizes[0] / (TLEN * IND);   // 4096
    gru_mfma14<<<B / NB, NTHR, 0, stream>>>(x, W_ih, W_hh, b_ih, b_hh, W_out, b_out, out);
}

// Round 9
// 246.151 us; speedup vs baseline: 1.3416x; 1.0786x over previous
//
#include <hip/hip_runtime.h>

#define HID 50
#define IND 8
#define TLEN 512
#define NB 16        // batch columns per block — all 16 MFMA N cols real
#define XTS 132      // x_frag per-timestep stride in halves (264B; full-resident x)
#define NTHR 448     // 7 waves, 2 M-tiles each (tiles 0..13)

typedef _Float16 f16x8 __attribute__((ext_vector_type(8)));
typedef _Float16 f16x4 __attribute__((ext_vector_type(4)));
typedef _Float16 f16x2 __attribute__((ext_vector_type(2)));
typedef float f32x4 __attribute__((ext_vector_type(4)));

// Round-19: R3 champion + full-resident x (all 512 timesteps staged once).
//  Ledger R1-R8: conflicts -3.2x -> 0; VALU -20% -> -20cyc; reads -43% -> 0;
//  deep-ILP -> +130; dual-group -> +480; NB=8 -> +340; flag-sync -> +130.
//  The 806-cyc step = LDS h-exchange round-trip + barrier + MFMA chain +
//  gate chain, all serial and irreducible at this geometry. The one
//  additive cut left: drop the 3 mid-loop chunk restages (2 barriers +
//  2048-unit burst each) by staging x for ALL 512 steps up front.
//  LDS: x 132KB + B 3.5KB + red 3.5KB = 139KB < 160KB (1 block/CU already).
__global__ __launch_bounds__(NTHR, 1) void gru_mfma15(
    const float* __restrict__ x,      // [B, T, 8]
    const float* __restrict__ W_ih,   // [150, 8]
    const float* __restrict__ W_hh,   // [150, 50]
    const float* __restrict__ b_ih,   // [150]
    const float* __restrict__ b_hh,   // [150]
    const float* __restrict__ W_out,  // [1, 50]
    const float* __restrict__ b_out,  // [1]
    float* __restrict__ out)          // [B]
{
    const int tid  = threadIdx.x;     // 448 threads = 7 waves
    const int wave = tid >> 6;
    const int lane = tid & 63;
    const int m16  = lane & 15;
    const int quad = lane >> 4;
    const int bb   = blockIdx.x;

    const int t0  = 2 * wave;         // tiles; R = 16*t + m16; R = 4*jh + g
    const int t1  = 2 * wave + 1;
    const int jh0 = 8 * wave + quad;
    const int jh1 = 8 * wave + 4 + quad;

    // B buffers: 2 x [7 kgrps][16 slots][8 halves] = 2 x 896 halves
    __shared__ _Float16 B_lds[2 * 896];
    __shared__ _Float16 x_frag[TLEN * XTS];   // 132 KB, all 512 steps resident
    __shared__ float    red[NB * 56];         // head scratch

    const int P[8] = {0, 4, 1, 5, 2, 6, 3, 7};

    // ---- one-time: A fragments + biases into VGPRs, scales prefolded ----
    auto aval = [&](int tt, int k) -> float {
        const int R  = 16 * tt + m16;
        const int rj = R >> 2;
        const int g  = R & 3;
        if (rj >= HID) return 0.f;
        const float sc = (g <= 1) ? -1.44269504f : 2.88539008f;
        float w = 0.f;
        if (g <= 1) {
            if (k < HID)      w = W_hh[(g * HID + rj) * HID + k];
            else if (k >= 56) w = W_ih[(g * HID + rj) * IND + (k - 56)];
        } else if (g == 2) {
            if (k < HID)      w = W_hh[(2 * HID + rj) * HID + k];
        } else {
            if (k >= 56)      w = W_ih[(2 * HID + rj) * IND + (k - 56)];
        }
        return sc * w;
    };

    f16x8 a00, a01, a10, a11;
#pragma unroll
    for (int p = 0; p < 8; ++p) {
        a00[p] = (_Float16)aval(t0, quad * 8 + P[p]);
        a01[p] = (_Float16)aval(t0, 32 + quad * 8 + P[p]);
        a10[p] = (_Float16)aval(t1, quad * 8 + P[p]);
        a11[p] = (_Float16)aval(t1, 32 + quad * 8 + P[p]);
    }

    auto mkbias = [&](int jh) -> f32x4 {
        f32x4 b = {0.f, 0.f, 0.f, 0.f};
        if (jh < HID) {
            b[0] = -1.44269504f * (b_ih[jh] + b_hh[jh]);
            b[1] = -1.44269504f * (b_ih[HID + jh] + b_hh[HID + jh]);
            b[2] =  2.88539008f * b_hh[2 * HID + jh];
            b[3] =  2.88539008f * b_ih[2 * HID + jh];
        }
        return b;
    };
    const f32x4 bias0 = mkbias(jh0);
    const f32x4 bias1 = mkbias(jh1);

    float h0 = 0.f, h1 = 0.f;

    // ---- stage ALL x: fragment order, permuted intra-slot (once) ----
    // x_frag[t*XTS + n*8 + p] = x[t][n][P[p]]
    {
        for (int u = tid; u < NB * TLEN; u += NTHR) {    // 8192 units
            const int n = u >> 9;                         // 0..15
            const int t = u & (TLEN - 1);
            const float4* s = (const float4*)(x + ((size_t)(bb * NB + n) * TLEN + t) * IND);
            const float4 va = s[0];                       // d 0..3
            const float4 vb = s[1];                       // d 4..7
            const f16x4 lo = {(_Float16)va.x, (_Float16)vb.x, (_Float16)va.y, (_Float16)vb.y};
            const f16x4 hi = {(_Float16)va.z, (_Float16)vb.z, (_Float16)va.w, (_Float16)vb.w};
            *(f16x4*)&x_frag[t * XTS + n * 8]     = lo;
            *(f16x4*)&x_frag[t * XTS + n * 8 + 4] = hi;
        }
    }

    // ---- init: zero both B buffers ----
    for (int idx = tid; idx < 2 * 896; idx += NTHR)
        B_lds[idx] = (_Float16)0.f;
    __syncthreads();

    const int lane8 = lane * 8;                       // halves: lane*16B
    const _Float16* xq = &x_frag[m16 * 8];            // quad3 x base
    const int wad = wave * 128 + m16 * 8 + 2 * quad;  // h-write base

    // 5-trans gates (scales prefolded): r = rcp(1+2^c0); Z = 2^c1;
    // E = 2^(c3 + r*c2); h' = (E*(Z+h) + (h-Z)) * rcp((E+1)*(Z+1))
    auto gates = [&](const f32x4& cc, float hh) -> float {
        const float R2 = __builtin_amdgcn_exp2f(cc[0]);
        const float r  = __builtin_amdgcn_rcpf(1.0f + R2);
        const float Z2 = __builtin_amdgcn_exp2f(cc[1]);
        const float E  = __builtin_amdgcn_exp2f(cc[3] + r * cc[2]);
        const float num = E * (Z2 + hh) + (hh - Z2);
        const float den = (E + 1.0f) * (Z2 + 1.0f);
        return num * __builtin_amdgcn_rcpf(den);
    };

    auto step = [&](int i, int cur, int nxt) {
        _Float16* Bc = &B_lds[cur * 896];
        _Float16* Bn = &B_lds[nxt * 896];
        const f16x8 bf0 = *(const f16x8*)(Bc + lane8);
        const _Float16* p1 = (quad == 3) ? (xq + (size_t)i * XTS) : (Bc + 512 + lane8);
        const f16x8 bf1 = *(const f16x8*)p1;
        f32x4 c0 = __builtin_amdgcn_mfma_f32_16x16x32_f16(a00, bf0, bias0, 0, 0, 0);
        f32x4 c1 = __builtin_amdgcn_mfma_f32_16x16x32_f16(a10, bf0, bias1, 0, 0, 0);
        c0 = __builtin_amdgcn_mfma_f32_16x16x32_f16(a01, bf1, c0, 0, 0, 0);
        c1 = __builtin_amdgcn_mfma_f32_16x16x32_f16(a11, bf1, c1, 0, 0, 0);
        h0 = gates(c0, h0);
        h1 = gates(c1, h1);
        *(f16x2*)(Bn + wad) = f16x2{(_Float16)h0, (_Float16)h1};
        __syncthreads();   // the only per-step barrier
    };

    // ---- recurrence: 7 waves, flat 512-step loop, 1 barrier/step ----
#pragma unroll 4
    for (int i = 0; i < TLEN; i += 2) {
        step(i,     0, 1);
        step(i + 1, 1, 0);
    }

    // ---- head: out[n] = sum_jh h(jh,n) * W_out[jh] + b_out ----
    if (jh0 < HID) red[m16 * 56 + jh0] = h0 * W_out[jh0];
    if (jh1 < HID) red[m16 * 56 + jh1] = h1 * W_out[jh1];
    __syncthreads();
    if (tid < NB) {
        float s = b_out[0];
        for (int j = 0; j < HID; ++j) s += red[tid * 56 + j];
        out[bb * NB + tid] = s;
    }
}

extern "C" void kernel_launch(void* const* d_in, const int* in_sizes, int n_in,
                              void* d_out, int out_size, void* d_ws, size_t ws_size,
                              hipStream_t stream) {
    const float* x     = (const float*)d_in[0];
    const float* W_ih  = (const float*)d_in[1];
    const float* W_hh  = (const float*)d_in[2];
    const float* b_ih  = (const float*)d_in[3];
    const float* b_hh  = (const float*)d_in[4];
    const float* W_out = (const float*)d_in[5];
    const float* b_out = (const float*)d_in[6];
    float* out = (float*)d_out;

    const int B = in_sizes[0] / (TLEN * IND);   // 4096
    gru_mfma15<<<B / NB, NTHR, 0, stream>>>(x, W_ih, W_hh, b_ih, b_hh, W_out, b_out, out);
}

// Round 10
// 232.863 us; speedup vs baseline: 1.4182x; 1.0571x over previous
//
#include <hip/hip_runtime.h>

#define HID 50
#define IND 8
#define TLEN 512
#define NB 16        // batch columns per block — all 16 MFMA N cols real
#define CH 128       // x chunk timesteps staged in LDS (4 chunks/sequence)
#define XTS 136      // x_frag per-timestep stride in halves (272B: 17*16B)
#define NTHR 448     // 7 waves, 2 M-tiles each, tiles 0..13 (rows >=200 dead, self-zero)

typedef _Float16 f16x8 __attribute__((ext_vector_type(8)));
typedef _Float16 f16x4 __attribute__((ext_vector_type(4)));
typedef _Float16 f16x2 __attribute__((ext_vector_type(2)));
typedef float f32x4 __attribute__((ext_vector_type(4)));

// Round-20: CHAMPION RESTORE (= Round-13 / gru_mfma9, 232.7 us bench).
//  R1-R9 ledger: conflicts -3.2x -> 0; VALU -20% -> -20cyc; reads -43% -> 0;
//  deep-ILP(1w/SIMD) -> +130; dual-group -> +480; NB=8 co-res -> +340;
//  flag-sync -> +130; full-resident x -> +40 (64KB ds-offset limit!).
//  The 806-cyc step = barrier + cross-wave h LDS round-trip + MFMA chain +
//  5-trans gate chain; ~280 cyc issue + ~500 cyc serial latency. All
//  structural alternatives measured worse. This kernel is the floor-holder.
__global__ __launch_bounds__(NTHR, 1) void gru_mfma9(
    const float* __restrict__ x,      // [B, T, 8]
    const float* __restrict__ W_ih,   // [150, 8]
    const float* __restrict__ W_hh,   // [150, 50]
    const float* __restrict__ b_ih,   // [150]
    const float* __restrict__ b_hh,   // [150]
    const float* __restrict__ W_out,  // [1, 50]
    const float* __restrict__ b_out,  // [1]
    float* __restrict__ out)          // [B]
{
    const int tid  = threadIdx.x;     // 448 threads = 7 waves
    const int wave = tid >> 6;
    const int lane = tid & 63;
    const int m16  = lane & 15;
    const int quad = lane >> 4;
    const int bb   = blockIdx.x;

    const int t0  = 2 * wave;         // tiles; R = 16*t + m16; R = 4*jh + g
    const int t1  = 2 * wave + 1;
    const int jh0 = 8 * wave + quad;          // kgrp = wave, j = quad
    const int jh1 = 8 * wave + 4 + quad;      // kgrp = wave, j = 4 + quad

    // B buffers: 2 x [7 kgrps][16 slots][8 halves] = 2 x 896 halves (1792B each)
    __shared__ _Float16 B_lds[2 * 896];
    __shared__ _Float16 x_frag[CH * XTS];     // ~34.8 KB, fragment-ordered x
    __shared__ float    red[NB * 56];         // head scratch

    // intra-slot k permutation: register half p holds k-offset P[p]
    const int P[8] = {0, 4, 1, 5, 2, 6, 3, 7};

    // ---- one-time: A fragments + biases into VGPRs, scales prefolded ----
    auto aval = [&](int tt, int k) -> float {
        const int R  = 16 * tt + m16;
        const int rj = R >> 2;
        const int g  = R & 3;
        if (rj >= HID) return 0.f;
        const float sc = (g <= 1) ? -1.44269504f : 2.88539008f;
        float w = 0.f;
        if (g <= 1) {
            if (k < HID)      w = W_hh[(g * HID + rj) * HID + k];
            else if (k >= 56) w = W_ih[(g * HID + rj) * IND + (k - 56)];
        } else if (g == 2) {
            if (k < HID)      w = W_hh[(2 * HID + rj) * HID + k];
        } else {
            if (k >= 56)      w = W_ih[(2 * HID + rj) * IND + (k - 56)];
        }
        return sc * w;
    };

    f16x8 a00, a01, a10, a11;
#pragma unroll
    for (int p = 0; p < 8; ++p) {
        a00[p] = (_Float16)aval(t0, quad * 8 + P[p]);
        a01[p] = (_Float16)aval(t0, 32 + quad * 8 + P[p]);
        a10[p] = (_Float16)aval(t1, quad * 8 + P[p]);
        a11[p] = (_Float16)aval(t1, 32 + quad * 8 + P[p]);
    }

    auto mkbias = [&](int jh) -> f32x4 {
        f32x4 b = {0.f, 0.f, 0.f, 0.f};
        if (jh < HID) {
            b[0] = -1.44269504f * (b_ih[jh] + b_hh[jh]);
            b[1] = -1.44269504f * (b_ih[HID + jh] + b_hh[HID + jh]);
            b[2] =  2.88539008f * b_hh[2 * HID + jh];
            b[3] =  2.88539008f * b_ih[2 * HID + jh];
        }
        return b;
    };
    const f32x4 bias0 = mkbias(jh0);
    const f32x4 bias1 = mkbias(jh1);

    float h0 = 0.f, h1 = 0.f;

    // ---- x chunk staging: fragment order, permuted intra-slot ----
    // x_frag[trel*XTS + n*8 + p] = x[t][n][P[p]]
    auto stage_chunk = [&](int c) {
        for (int u = tid; u < NB * CH; u += NTHR) {      // 2048 units
            const int n    = u >> 7;
            const int trel = u & (CH - 1);
            const float4* s = (const float4*)(x + ((size_t)(bb * NB + n) * TLEN + (size_t)c * CH + trel) * IND);
            const float4 va = s[0];                       // d 0..3
            const float4 vb = s[1];                       // d 4..7
            const f16x4 lo = {(_Float16)va.x, (_Float16)vb.x, (_Float16)va.y, (_Float16)vb.y};
            const f16x4 hi = {(_Float16)va.z, (_Float16)vb.z, (_Float16)va.w, (_Float16)vb.w};
            *(f16x4*)&x_frag[trel * XTS + n * 8]     = lo;
            *(f16x4*)&x_frag[trel * XTS + n * 8 + 4] = hi;
        }
    };

    // ---- init: zero both B buffers; stage chunk 0 ----
    for (int idx = tid; idx < 2 * 896; idx += NTHR)
        B_lds[idx] = (_Float16)0.f;
    stage_chunk(0);
    __syncthreads();

    const int lane8 = lane * 8;                       // halves: lane*16B
    const _Float16* xq = &x_frag[m16 * 8];            // quad3 x base
    // write slot: kgrp=wave, slot=m16, halves 2q (h0) and 2q+1 (h1) — adjacent
    const int wad = wave * 128 + m16 * 8 + 2 * quad;  // halves within a buffer

    // 5-trans gates (scales prefolded): r = rcp(1+2^c0); Z = 2^c1;
    // E = 2^(c3 + r*c2); h' = (E*(Z+h) + (h-Z)) * rcp((E+1)*(Z+1))
    auto gates = [&](const f32x4& cc, float h) -> float {
        const float R2 = __builtin_amdgcn_exp2f(cc[0]);
        const float r  = __builtin_amdgcn_rcpf(1.0f + R2);
        const float Z2 = __builtin_amdgcn_exp2f(cc[1]);
        const float E  = __builtin_amdgcn_exp2f(cc[3] + r * cc[2]);
        const float num = E * (Z2 + h) + (h - Z2);
        const float den = (E + 1.0f) * (Z2 + 1.0f);
        return num * __builtin_amdgcn_rcpf(den);
    };

    auto step = [&](int i, int cur, int nxt) {
        _Float16* Bc = &B_lds[cur * 896];
        _Float16* Bn = &B_lds[nxt * 896];
        const f16x8 bf0 = *(const f16x8*)(Bc + lane8);
        const _Float16* p1 = (quad == 3) ? (xq + (size_t)i * XTS) : (Bc + 512 + lane8);
        const f16x8 bf1 = *(const f16x8*)p1;
        f32x4 c0 = __builtin_amdgcn_mfma_f32_16x16x32_f16(a00, bf0, bias0, 0, 0, 0);
        f32x4 c1 = __builtin_amdgcn_mfma_f32_16x16x32_f16(a10, bf0, bias1, 0, 0, 0);
        c0 = __builtin_amdgcn_mfma_f32_16x16x32_f16(a01, bf1, c0, 0, 0, 0);
        c1 = __builtin_amdgcn_mfma_f32_16x16x32_f16(a11, bf1, c1, 0, 0, 0);
        h0 = gates(c0, h0);
        h1 = gates(c1, h1);
        *(f16x2*)(Bn + wad) = f16x2{(_Float16)h0, (_Float16)h1};
        __syncthreads();   // the only per-step barrier
    };

    // ---- recurrence: 7 waves, 1 barrier/step ----
    for (int c = 0; c < 4; ++c) {
        if (c != 0) { stage_chunk(c); __syncthreads(); }
#pragma unroll 4
        for (int i = 0; i < CH; i += 2) {
            step(i,     0, 1);
            step(i + 1, 1, 0);
        }
    }

    // ---- head: out[n] = sum_jh h(jh,n) * W_out[jh] + b_out ----
    if (jh0 < HID) red[m16 * 56 + jh0] = h0 * W_out[jh0];
    if (jh1 < HID) red[m16 * 56 + jh1] = h1 * W_out[jh1];
    __syncthreads();
    if (tid < NB) {
        float s = b_out[0];
        for (int j = 0; j < HID; ++j) s += red[tid * 56 + j];
        out[bb * NB + tid] = s;
    }
}

extern "C" void kernel_launch(void* const* d_in, const int* in_sizes, int n_in,
                              void* d_out, int out_size, void* d_ws, size_t ws_size,
                              hipStream_t stream) {
    const float* x     = (const float*)d_in[0];
    const float* W_ih  = (const float*)d_in[1];
    const float* W_hh  = (const float*)d_in[2];
    const float* b_ih  = (const float*)d_in[3];
    const float* b_hh  = (const float*)d_in[4];
    const float* W_out = (const float*)d_in[5];
    const float* b_out = (const float*)d_in[6];
    float* out = (float*)d_out;

    const int B = in_sizes[0] / (TLEN * IND);   // 4096
    gru_mfma9<<<B / NB, NTHR, 0, stream>>>(x, W_ih, W_hh, b_ih, b_hh, W_out, b_out, out);
}